// Round 10
// baseline (2715.481 us; speedup 1.0000x reference)
//
#include <hip/hip_runtime.h>
#include <hip/hip_fp16.h>

// LSTM forecast: B=256, T_past=512, HID=512, FEAT=1, future=64 -> 576 steps.
// Grid: 128 WGs x 512 threads = 16 batch-groups (bb) x 8 hidden-groups (gb).
// Each WG: 16 batch x 64 hidden. W_hh slice persistent in fp16 MFMA B-frags.
//
// Lessons:
// R1: ordered atomics/fences -> wbl2/inv flushes. Use RELAXED agent ops.
// R5 (1968): deferred atomics, 3 barriers. R6-R8: no XCD scope; sub-agent
//     exchange DEAD (SE-scope staleness; token test).
// R9 (1662): zero-atomic out[]. R11 (1636): BEST; incremental per-producer
//     poll/load + own-slice direct hcur write.
// R12 (2506) / R16 (1719) / R17 (1734): tag-in-data family. R16/R17 removed
//     drain+barrierB+flag entirely and FUSED detect+data -- no gain.
//     CONCLUSION: per-step cost is a FIXED store->visibility window (~1.4us
//     at MALL) + overheads, not consumer chain length. sc1 (agent) loads
//     proven correct on HW by R16/R17 passes.
// R13 (2670): per-wave flags, 64 writers on ONE line + 56 pollers: bounced.
// R14 (1789): per-wave flags in 8 SEPARATE lines: 8 poll requests/iter.
// R15 (1753): delegated poll + LDS relay: no gain (poller count irrelevant).
// Multi-group-per-WG analysis: work/group-step ~0.45us; G groups add
//     G*0.45us serial work to hide ~1.4us latency -> nets ~zero. Skipped.
// R18: R11 + PACKED per-wave flags + sc1 loads. Producer WG's 8 wave-flags
//     live in ONE 32B segment (8 dwords): consumer wave w polls producer
//     w's line with a single coalesced 32B read (R11's proven poll shape;
//     8 one-shot writers/line like R11). Each wave drains ITS OWN stores
//     (vmcnt per-wave) and lane0 posts its flag immediately -> barrier B
//     DELETED; flags land incrementally; consumer detect overlaps producer
//     stragglers. Fixes R13 (writerx64) and R14 (8-line poll) layout bugs.

#define TPAST 512
#define TTOT  576
#define HIDN  512
#define BW    16            // batch per WG
#define HW    64            // hidden per WG
#define NWG   128
#define NTHR  512
#define HSTR  520           // hcur LDS row stride (fp16); *2B=1040, 16B-aligned
#define GSTR  261           // gates LDS row stride (fp32)
#define BATCHN 256

typedef _Float16 half8   __attribute__((ext_vector_type(8)));
typedef _Float16 half2v  __attribute__((ext_vector_type(2)));
typedef float    float4v __attribute__((ext_vector_type(4)));
typedef int      int4v   __attribute__((ext_vector_type(4)));

__device__ __forceinline__ float fast_exp(float x) {
    return __builtin_amdgcn_exp2f(x * 1.44269504f);
}
__device__ __forceinline__ float fast_sigmoid(float x) {
    return __builtin_amdgcn_rcpf(1.0f + fast_exp(-x));
}
__device__ __forceinline__ float fast_tanh(float x) {
    return 1.0f - 2.0f * __builtin_amdgcn_rcpf(fast_exp(2.0f * x) + 1.0f);
}

// 32B agent-scope load (sc1): bypasses L1/L2, reads fresh at MALL.
__device__ __forceinline__ void ld32_agent(const void* p, int4v& a, int4v& b) {
    asm volatile("global_load_dwordx4 %0, %2, off sc1\n\t"
                 "global_load_dwordx4 %1, %2, off offset:16 sc1\n\t"
                 "s_waitcnt vmcnt(0)"
                 : "=v"(a), "=v"(b) : "v"(p) : "memory");
}
__device__ __forceinline__ void drain_vm() {
    asm volatile("s_waitcnt vmcnt(0)" ::: "memory");
}

__global__ __launch_bounds__(NTHR, 1)
void lstm_forecast_kernel(const float* __restrict__ xseq,
                          const float* __restrict__ Wih,
                          const float* __restrict__ Whh,
                          const float* __restrict__ bih,
                          const float* __restrict__ bhh,
                          const float* __restrict__ Wdec,
                          const float* __restrict__ bdec,
                          float* __restrict__ out,
                          unsigned int* __restrict__ flagbase,
                          unsigned int* __restrict__ hbuf)   // fp16 pairs, [2][256][512]
{
    __shared__ _Float16 hcur[BW * HSTR];   // current h tile, fp16, row=batch
    __shared__ float    gates[BW * GSTR];  // staged MFMA output (16 x 256)
    __shared__ float    wdecs[HIDN];       // W_dec row
    __shared__ float    xcur[BW];

    const int tid  = threadIdx.x;
    const int bb   = blockIdx.x & 15;      // batch group
    const int gb   = blockIdx.x >> 4;      // hidden group 0..7
    const int lane = tid & 63;
    const int wave = tid >> 6;             // 0..7
    const int m    = lane & 15;            // MFMA A-row / D-col
    const int q    = lane >> 4;            // MFMA quad

    // ---- persistent W_hh B-fragments: 2 col-blocks x 16 k-steps ----
    half8 Wf[2][16];
    {
        #pragma unroll
        for (int cbi = 0; cbi < 2; ++cbi) {
            const int col = (2 * wave + cbi) * 16 + m;        // 0..255
            const int gt  = col >> 6;                          // 0=i 1=f 2=g 3=o
            const int jl  = col & 63;
            const float* wr = Whh + (size_t)(gt * HIDN + gb * HW + jl) * HIDN;
            #pragma unroll
            for (int kk = 0; kk < 16; ++kk) {
                const int k0 = kk * 32 + q * 8;
                float4v u = *(const float4v*)(wr + k0);
                float4v v = *(const float4v*)(wr + k0 + 4);
                half8 h;
                h[0] = (_Float16)u[0]; h[1] = (_Float16)u[1];
                h[2] = (_Float16)u[2]; h[3] = (_Float16)u[3];
                h[4] = (_Float16)v[0]; h[5] = (_Float16)v[1];
                h[6] = (_Float16)v[2]; h[7] = (_Float16)v[3];
                Wf[cbi][kk] = h;
            }
        }
    }

    // ---- per-thread elementwise constants: thread -> (batch eb, hidden j0,j0+1)
    const int eb = tid >> 5;               // 0..15 (wave w owns rows 2w,2w+1)
    const int jj = tid & 31;
    const int j0 = 2 * jj;                 // 0..62
    float wih_r[2][4], bsum_r[2][4];
    #pragma unroll
    for (int p = 0; p < 2; ++p) {
        const int jg = gb * HW + j0 + p;
        #pragma unroll
        for (int gt = 0; gt < 4; ++gt) {
            const int r = gt * HIDN + jg;
            wih_r[p][gt]  = Wih[r];
            bsum_r[p][gt] = bih[r] + bhh[r];
        }
    }
    const float bdecv = bdec[0];
    float c0 = 0.01f, c1 = 0.01f;

    // ---- init ----
    {
        const _Float16 hinit = (_Float16)0.01f;
        for (int i = tid; i < BW * HSTR; i += NTHR) hcur[i] = hinit;
        wdecs[tid] = Wdec[tid];            // HIDN == NTHR
        if (tid < BW) xcur[tid] = xseq[(bb * BW + tid) * TPAST + 0];
    }
    __syncthreads();

    // flag layout: 64B line per (bb, producer-WG); first 8 dwords = that
    // WG's 8 wave-flags. One-shot writers x8, coalesced 32B polls.
    unsigned int* wfl_own =
        flagbase + (size_t)(((bb << 3) | gb) * 16 + wave);
    const unsigned int* pollline =
        flagbase + (size_t)(((bb << 3) | wave) * 16);  // producer 'wave' line
    const int bglob_e = bb * BW + eb;

    for (int t = 0; t < TTOT; ++t) {
        // ---- phase 1: MFMA  gates_tile = h (16x512) * W^T (512x256) ----
        float4v acc0 = {0.f, 0.f, 0.f, 0.f};
        float4v acc1 = {0.f, 0.f, 0.f, 0.f};
        const _Float16* arow = hcur + m * HSTR + q * 8;
        #pragma unroll
        for (int kk = 0; kk < 16; ++kk) {
            half8 af = *(const half8*)(arow + kk * 32);
            acc0 = __builtin_amdgcn_mfma_f32_16x16x32_f16(af, Wf[0][kk], acc0, 0, 0, 0);
            acc1 = __builtin_amdgcn_mfma_f32_16x16x32_f16(af, Wf[1][kk], acc1, 0, 0, 0);
        }
        // ---- phase 2: stage gates to LDS (C layout: col=m, row=q*4+r) ----
        {
            const int colbase = wave * 32;
            #pragma unroll
            for (int r = 0; r < 4; ++r) {
                gates[(q * 4 + r) * GSTR + colbase +      m] = acc0[r];
                gates[(q * 4 + r) * GSTR + colbase + 16 + m] = acc1[r];
            }
        }
        // prefetch next past-input (latency hides under barrier A + phase 3)
        const int tn = t + 1;
        float xq = 0.f;
        if (tn < TPAST && tid < BW) xq = xseq[(bb * BW + tid) * TPAST + tn];

        __syncthreads();   // barrier A: gates ready; hcur reads complete

        // ---- phase 3: elementwise LSTM + h store ----
        {
            const float xc = xcur[eb];
            const float* grow = gates + eb * GSTR;

            float gi = grow[       j0] + xc * wih_r[0][0] + bsum_r[0][0];
            float gf = grow[ 64  + j0] + xc * wih_r[0][1] + bsum_r[0][1];
            float gg = grow[128  + j0] + xc * wih_r[0][2] + bsum_r[0][2];
            float go = grow[192  + j0] + xc * wih_r[0][3] + bsum_r[0][3];
            c0 = fast_sigmoid(gf) * c0 + fast_sigmoid(gi) * fast_tanh(gg);
            const float h0 = fast_sigmoid(go) * fast_tanh(c0);

            gi = grow[       j0 + 1] + xc * wih_r[1][0] + bsum_r[1][0];
            gf = grow[ 64  + j0 + 1] + xc * wih_r[1][1] + bsum_r[1][1];
            gg = grow[128  + j0 + 1] + xc * wih_r[1][2] + bsum_r[1][2];
            go = grow[192  + j0 + 1] + xc * wih_r[1][3] + bsum_r[1][3];
            c1 = fast_sigmoid(gf) * c1 + fast_sigmoid(gi) * fast_tanh(gg);
            const float h1 = fast_sigmoid(go) * fast_tanh(c1);

            half2v hp; hp[0] = (_Float16)h0; hp[1] = (_Float16)h1;

            // own-slice direct write into hcur (safe: after barrier A)
            *(half2v*)(hcur + eb * HSTR + gb * HW + j0) = hp;

            const unsigned int bits = __builtin_bit_cast(unsigned int, hp);
            unsigned int* hdst = hbuf
                + (size_t)((tn & 1) * BATCHN + bglob_e) * (HIDN / 2)
                + gb * (HW / 2) + jj;
            __hip_atomic_store(hdst, bits, __ATOMIC_RELAXED,
                               __HIP_MEMORY_SCOPE_AGENT);
        }

        // ---- phase 4: per-wave arrive (no barrier B) ----
        // vmcnt is per-wave: drain THIS wave's h stores, then post its flag.
        const unsigned int target = (unsigned int)tn;
        drain_vm();
        if (lane == 0)
            __hip_atomic_store(wfl_own, target, __ATOMIC_RELAXED,
                               __HIP_MEMORY_SCOPE_AGENT);

        // ---- phase 5: consumer poll (producer's 8 wave-flags, 1 line) ----
        if (wave != gb) {
            const unsigned int* slot = pollline + (lane & 7);   // 32B, one line
            int guard = 0;
            for (;;) {
                const unsigned int v = __hip_atomic_load(
                    slot, __ATOMIC_RELAXED, __HIP_MEMORY_SCOPE_AGENT);
                if (__ballot(v >= target) == ~0ull) break;
                __builtin_amdgcn_s_sleep(1);
                if (++guard > (1 << 20)) break;   // fail loud, not hung
            }
            __builtin_amdgcn_sched_barrier(0);   // keep loads below the spin

            const int p1 = tn & 1;
            const char* src = (const char*)hbuf
                + ((size_t)(p1 * BATCHN + bb * BW)) * (HIDN * 2)  // tile base
                + (size_t)(lane >> 2) * (HIDN * 2)                // row 0..15
                + wave * (HW * 2)                                 // producer cols
                + (lane & 3) * 32;                                // 32B chunk
            int4v a, b;
            ld32_agent(src, a, b);
            _Float16* dst = hcur + (lane >> 2) * HSTR + wave * HW
                            + (lane & 3) * 16;
            *(int4v*)(dst)     = a;
            *(int4v*)(dst + 8) = b;
        }
        __syncthreads();   // barrier C: full h(t) tile in hcur

        // ---- phase 6: decoder from the full fresh tile ----
        // out rows 2gb,2gb+1 by waves 0,1 (balanced: 2 rows/WG, plain stores)
        if (wave < 2) {
            const int brow = 2 * gb + wave;              // 0..15
            const _Float16* hr = hcur + brow * HSTR + lane * 8;
            const float*    wr = wdecs + lane * 8;
            half8 hv = *(const half8*)hr;
            float dx = 0.f;
            #pragma unroll
            for (int e = 0; e < 8; ++e) dx += (float)hv[e] * wr[e];
            dx += __shfl_down(dx, 32);
            dx += __shfl_down(dx, 16);
            dx += __shfl_down(dx, 8);
            dx += __shfl_down(dx, 4);
            dx += __shfl_down(dx, 2);
            dx += __shfl_down(dx, 1);
            if (lane == 0)
                out[(bb * BW + brow) * TTOT + t] = dx + bdecv;
        }
        // future x_{t+1} for all 16 rows (wave w covers its own rows 2w,2w+1)
        if (tn >= TPAST) {
            const _Float16* hr = hcur + eb * HSTR + jj * 16;
            const float*    wr = wdecs + jj * 16;
            float dx = 0.f;
            #pragma unroll
            for (int u = 0; u < 2; ++u) {
                half8 hv = *(const half8*)(hr + u * 8);
                #pragma unroll
                for (int e = 0; e < 8; ++e)
                    dx += (float)hv[e] * wr[u * 8 + e];
            }
            dx += __shfl_down(dx, 16);
            dx += __shfl_down(dx, 8);
            dx += __shfl_down(dx, 4);
            dx += __shfl_down(dx, 2);
            dx += __shfl_down(dx, 1);
            if ((lane & 31) == 0) xcur[eb] = dx + bdecv;  // own-wave write/read
        } else {
            if (tid < BW) xcur[tid] = xq;  // cross-wave reads ordered by barrier A
        }
    }
}

extern "C" void kernel_launch(void* const* d_in, const int* in_sizes, int n_in,
                              void* d_out, int out_size, void* d_ws, size_t ws_size,
                              hipStream_t stream) {
    (void)in_sizes; (void)n_in; (void)ws_size; (void)out_size;
    const float* xseq = (const float*)d_in[0];
    // d_in[1] = future_n scalar (fixed 64, shapes hardcoded)
    const float* Wih  = (const float*)d_in[2];
    const float* Whh  = (const float*)d_in[3];
    const float* bih  = (const float*)d_in[4];
    const float* bhh  = (const float*)d_in[5];
    const float* Wdec = (const float*)d_in[6];
    const float* bdec = (const float*)d_in[7];
    float* out = (float*)d_out;

    unsigned int* flags = (unsigned int*)d_ws;                // 16x8 x 64B lines
    unsigned int* hbuf  = (unsigned int*)((char*)d_ws + 8192);// [2][256][512] fp16 pairs

    hipMemsetAsync(d_ws, 0, 8192, stream);
    // no d_out memset needed: every (b,t) gets exactly one plain store
    lstm_forecast_kernel<<<dim3(NWG), dim3(NTHR), 0, stream>>>(
        xseq, Wih, Whh, bih, bhh, Wdec, bdec, out, flags, hbuf);
}

// Round 11
// 1661.773 us; speedup vs baseline: 1.6341x; 1.6341x over previous
//
#include <hip/hip_runtime.h>
#include <hip/hip_fp16.h>

// LSTM forecast: B=256, T_past=512, HID=512, FEAT=1, future=64 -> 576 steps.
// Grid: 128 WGs x 512 threads = 16 batch-groups (bb) x 8 hidden-groups (gb).
// Each WG: 16 batch x 64 hidden. W_hh slice persistent in fp16 MFMA B-frags.
//
// FINAL STRUCTURE (R11, 1636us): every structural deviation tried in
// R12-R18 regressed or was neutral. The step floor is the fixed cross-WG
// agent-scope visibility latency (store -> flag -> load ~2.2us/step),
// paid 576 times sequentially; counters show ~85% stall with traffic far
// below BW ceilings -> latency roofline of the synchronization fabric.
//
// Lessons:
// R1: ordered atomics/fences -> wbl2/inv flushes. Use RELAXED agent ops.
// R5 (1968): deferred atomics, 3 barriers. R6-R8: no XCD scope; sub-agent
//     exchange DEAD (SE-scope staleness; token test).
// R9 (1662): zero-atomic out[]; post-barrier-C decode, plain stores.
// R11 (1636): BEST. incremental per-producer poll/load + own-slice direct
//     hcur write; drain -> barrier B -> ONE flag store/WG -> each consumer
//     wave polls its producer's single 32B line -> 32B/lane slice load.
// R12 (2506): fp32 tag-in-data @ system scope. R16 (1719) / R17 (1734):
//     fp16 tag-in-data, incl. fused poll-is-load: no gain. Chain length
//     is not the cost; the visibility window is.
// R13 (2670) / R14 (1789) / R18 (2620): per-wave flags in 3 layouts: all
//     regress (8 flag stores/WG/step multiply RMW pressure on read-hot
//     flag lines). R15 (1753): delegated poll + LDS relay: no gain.
// Multi-group-per-WG: analytically net-zero (0.45us work/group-step added
//     per group vs ~1.4us hidden). Skipped.

#define TPAST 512
#define TTOT  576
#define HIDN  512
#define BW    16            // batch per WG
#define HW    64            // hidden per WG
#define NGRP  8             // WGs per batch group
#define NWG   128
#define NTHR  512
#define HSTR  520           // hcur LDS row stride (fp16); *2B=1040, 16B-aligned
#define GSTR  261           // gates LDS row stride (fp32)
#define BATCHN 256

typedef _Float16 half8   __attribute__((ext_vector_type(8)));
typedef _Float16 half2v  __attribute__((ext_vector_type(2)));
typedef float    float4v __attribute__((ext_vector_type(4)));
typedef int      int4v   __attribute__((ext_vector_type(4)));

__device__ __forceinline__ float fast_exp(float x) {
    return __builtin_amdgcn_exp2f(x * 1.44269504f);
}
__device__ __forceinline__ float fast_sigmoid(float x) {
    return __builtin_amdgcn_rcpf(1.0f + fast_exp(-x));
}
__device__ __forceinline__ float fast_tanh(float x) {
    return 1.0f - 2.0f * __builtin_amdgcn_rcpf(fast_exp(2.0f * x) + 1.0f);
}

// 32B system-scope load (sc0 sc1): bypasses L1/L2, reads fresh at MALL.
__device__ __forceinline__ void ld32_sys(const void* p, int4v& a, int4v& b) {
    asm volatile("global_load_dwordx4 %0, %2, off sc0 sc1\n\t"
                 "global_load_dwordx4 %1, %2, off offset:16 sc0 sc1\n\t"
                 "s_waitcnt vmcnt(0)"
                 : "=v"(a), "=v"(b) : "v"(p) : "memory");
}
__device__ __forceinline__ void drain_vm() {
    asm volatile("s_waitcnt vmcnt(0)" ::: "memory");
}

__global__ __launch_bounds__(NTHR, 1)
void lstm_forecast_kernel(const float* __restrict__ xseq,
                          const float* __restrict__ Wih,
                          const float* __restrict__ Whh,
                          const float* __restrict__ bih,
                          const float* __restrict__ bhh,
                          const float* __restrict__ Wdec,
                          const float* __restrict__ bdec,
                          float* __restrict__ out,
                          unsigned int* __restrict__ flagbase,
                          unsigned int* __restrict__ hbuf)   // fp16 pairs, [2][256][512]
{
    __shared__ _Float16 hcur[BW * HSTR];   // current h tile, fp16, row=batch
    __shared__ float    gates[BW * GSTR];  // staged MFMA output (16 x 256)
    __shared__ float    wdecs[HIDN];       // W_dec row
    __shared__ float    xcur[BW];

    const int tid  = threadIdx.x;
    const int bb   = blockIdx.x & 15;      // batch group
    const int gb   = blockIdx.x >> 4;      // hidden group 0..7
    const int lane = tid & 63;
    const int wave = tid >> 6;             // 0..7
    const int m    = lane & 15;            // MFMA A-row / D-col
    const int q    = lane >> 4;            // MFMA quad

    // ---- persistent W_hh B-fragments: 2 col-blocks x 16 k-steps ----
    half8 Wf[2][16];
    {
        #pragma unroll
        for (int cbi = 0; cbi < 2; ++cbi) {
            const int col = (2 * wave + cbi) * 16 + m;        // 0..255
            const int gt  = col >> 6;                          // 0=i 1=f 2=g 3=o
            const int jl  = col & 63;
            const float* wr = Whh + (size_t)(gt * HIDN + gb * HW + jl) * HIDN;
            #pragma unroll
            for (int kk = 0; kk < 16; ++kk) {
                const int k0 = kk * 32 + q * 8;
                float4v u = *(const float4v*)(wr + k0);
                float4v v = *(const float4v*)(wr + k0 + 4);
                half8 h;
                h[0] = (_Float16)u[0]; h[1] = (_Float16)u[1];
                h[2] = (_Float16)u[2]; h[3] = (_Float16)u[3];
                h[4] = (_Float16)v[0]; h[5] = (_Float16)v[1];
                h[6] = (_Float16)v[2]; h[7] = (_Float16)v[3];
                Wf[cbi][kk] = h;
            }
        }
    }

    // ---- per-thread elementwise constants: thread -> (batch eb, hidden j0,j0+1)
    const int eb = tid >> 5;               // 0..15 (wave w owns rows 2w,2w+1)
    const int jj = tid & 31;
    const int j0 = 2 * jj;                 // 0..62
    float wih_r[2][4], bsum_r[2][4];
    #pragma unroll
    for (int p = 0; p < 2; ++p) {
        const int jg = gb * HW + j0 + p;
        #pragma unroll
        for (int gt = 0; gt < 4; ++gt) {
            const int r = gt * HIDN + jg;
            wih_r[p][gt]  = Wih[r];
            bsum_r[p][gt] = bih[r] + bhh[r];
        }
    }
    const float bdecv = bdec[0];
    float c0 = 0.01f, c1 = 0.01f;

    // ---- init ----
    {
        const _Float16 hinit = (_Float16)0.01f;
        for (int i = tid; i < BW * HSTR; i += NTHR) hcur[i] = hinit;
        wdecs[tid] = Wdec[tid];            // HIDN == NTHR
        if (tid < BW) xcur[tid] = xseq[(bb * BW + tid) * TPAST + 0];
    }
    __syncthreads();

    unsigned int* gflags = flagbase + bb * 16;   // 64B flag line per group
    const int bglob_e = bb * BW + eb;

    for (int t = 0; t < TTOT; ++t) {
        // ---- phase 1: MFMA  gates_tile = h (16x512) * W^T (512x256) ----
        float4v acc0 = {0.f, 0.f, 0.f, 0.f};
        float4v acc1 = {0.f, 0.f, 0.f, 0.f};
        const _Float16* arow = hcur + m * HSTR + q * 8;
        #pragma unroll
        for (int kk = 0; kk < 16; ++kk) {
            half8 af = *(const half8*)(arow + kk * 32);
            acc0 = __builtin_amdgcn_mfma_f32_16x16x32_f16(af, Wf[0][kk], acc0, 0, 0, 0);
            acc1 = __builtin_amdgcn_mfma_f32_16x16x32_f16(af, Wf[1][kk], acc1, 0, 0, 0);
        }
        // ---- phase 2: stage gates to LDS (C layout: col=m, row=q*4+r) ----
        {
            const int colbase = wave * 32;
            #pragma unroll
            for (int r = 0; r < 4; ++r) {
                gates[(q * 4 + r) * GSTR + colbase +      m] = acc0[r];
                gates[(q * 4 + r) * GSTR + colbase + 16 + m] = acc1[r];
            }
        }
        // prefetch next past-input (latency hides under barrier A + phase 3)
        const int tn = t + 1;
        float xq = 0.f;
        if (tn < TPAST && tid < BW) xq = xseq[(bb * BW + tid) * TPAST + tn];

        __syncthreads();   // barrier A: gates ready; hcur reads complete

        // ---- phase 3: elementwise LSTM + h store ----
        {
            const float xc = xcur[eb];
            const float* grow = gates + eb * GSTR;

            float gi = grow[       j0] + xc * wih_r[0][0] + bsum_r[0][0];
            float gf = grow[ 64  + j0] + xc * wih_r[0][1] + bsum_r[0][1];
            float gg = grow[128  + j0] + xc * wih_r[0][2] + bsum_r[0][2];
            float go = grow[192  + j0] + xc * wih_r[0][3] + bsum_r[0][3];
            c0 = fast_sigmoid(gf) * c0 + fast_sigmoid(gi) * fast_tanh(gg);
            const float h0 = fast_sigmoid(go) * fast_tanh(c0);

            gi = grow[       j0 + 1] + xc * wih_r[1][0] + bsum_r[1][0];
            gf = grow[ 64  + j0 + 1] + xc * wih_r[1][1] + bsum_r[1][1];
            gg = grow[128  + j0 + 1] + xc * wih_r[1][2] + bsum_r[1][2];
            go = grow[192  + j0 + 1] + xc * wih_r[1][3] + bsum_r[1][3];
            c1 = fast_sigmoid(gf) * c1 + fast_sigmoid(gi) * fast_tanh(gg);
            const float h1 = fast_sigmoid(go) * fast_tanh(c1);

            half2v hp; hp[0] = (_Float16)h0; hp[1] = (_Float16)h1;

            // own-slice direct write into hcur (safe: after barrier A)
            *(half2v*)(hcur + eb * HSTR + gb * HW + j0) = hp;

            const unsigned int bits = __builtin_bit_cast(unsigned int, hp);
            unsigned int* hdst = hbuf
                + (size_t)((tn & 1) * BATCHN + bglob_e) * (HIDN / 2)
                + gb * (HW / 2) + jj;
            __hip_atomic_store(hdst, bits, __ATOMIC_RELAXED,
                               __HIP_MEMORY_SCOPE_AGENT);
        }

        drain_vm();        // per-wave: h stores ack'd at MALL
        __syncthreads();   // barrier B: all waves drained

        // ---- phase 4+5: arrive + incremental per-producer poll/load ----
        const unsigned int target = (unsigned int)tn;
        if (wave == gb && lane == 0)
            __hip_atomic_store(gflags + gb, target, __ATOMIC_RELAXED,
                               __HIP_MEMORY_SCOPE_AGENT);
        if (wave != gb) {
            // wave w consumes producer w's 64-col slice (16 rows x 128B)
            const unsigned int* slot = gflags + wave;
            int guard = 0;
            for (;;) {
                const unsigned int v = __hip_atomic_load(
                    slot, __ATOMIC_RELAXED, __HIP_MEMORY_SCOPE_AGENT);
                if (v >= target) break;
                __builtin_amdgcn_s_sleep(1);
                if (++guard > (1 << 22)) break;   // fail loud, not hung
            }
            __builtin_amdgcn_sched_barrier(0);   // keep loads below the spin

            const int p1 = tn & 1;
            const char* src = (const char*)hbuf
                + ((size_t)(p1 * BATCHN + bb * BW)) * (HIDN * 2)  // tile base
                + (size_t)(lane >> 2) * (HIDN * 2)                // row 0..15
                + wave * (HW * 2)                                 // producer cols
                + (lane & 3) * 32;                                // 32B chunk
            int4v a, b;
            ld32_sys(src, a, b);
            _Float16* dst = hcur + (lane >> 2) * HSTR + wave * HW
                            + (lane & 3) * 16;
            *(int4v*)(dst)     = a;
            *(int4v*)(dst + 8) = b;
        }
        __syncthreads();   // barrier C: full h(t) tile in hcur

        // ---- phase 6: decoder from the full fresh tile ----
        // out rows 2gb,2gb+1 by waves 0,1 (balanced: 2 rows/WG, plain stores)
        if (wave < 2) {
            const int brow = 2 * gb + wave;              // 0..15
            const _Float16* hr = hcur + brow * HSTR + lane * 8;
            const float*    wr = wdecs + lane * 8;
            half8 hv = *(const half8*)hr;
            float dx = 0.f;
            #pragma unroll
            for (int e = 0; e < 8; ++e) dx += (float)hv[e] * wr[e];
            dx += __shfl_down(dx, 32);
            dx += __shfl_down(dx, 16);
            dx += __shfl_down(dx, 8);
            dx += __shfl_down(dx, 4);
            dx += __shfl_down(dx, 2);
            dx += __shfl_down(dx, 1);
            if (lane == 0)
                out[(bb * BW + brow) * TTOT + t] = dx + bdecv;
        }
        // future x_{t+1} for all 16 rows (wave w covers its own rows 2w,2w+1)
        if (tn >= TPAST) {
            const _Float16* hr = hcur + eb * HSTR + jj * 16;
            const float*    wr = wdecs + jj * 16;
            float dx = 0.f;
            #pragma unroll
            for (int u = 0; u < 2; ++u) {
                half8 hv = *(const half8*)(hr + u * 8);
                #pragma unroll
                for (int e = 0; e < 8; ++e)
                    dx += (float)hv[e] * wr[u * 8 + e];
            }
            dx += __shfl_down(dx, 16);
            dx += __shfl_down(dx, 8);
            dx += __shfl_down(dx, 4);
            dx += __shfl_down(dx, 2);
            dx += __shfl_down(dx, 1);
            if ((lane & 31) == 0) xcur[eb] = dx + bdecv;  // own-wave write/read
        } else {
            if (tid < BW) xcur[tid] = xq;  // cross-wave reads ordered by barrier A
        }
    }
}

extern "C" void kernel_launch(void* const* d_in, const int* in_sizes, int n_in,
                              void* d_out, int out_size, void* d_ws, size_t ws_size,
                              hipStream_t stream) {
    (void)in_sizes; (void)n_in; (void)ws_size; (void)out_size;
    const float* xseq = (const float*)d_in[0];
    // d_in[1] = future_n scalar (fixed 64, shapes hardcoded)
    const float* Wih  = (const float*)d_in[2];
    const float* Whh  = (const float*)d_in[3];
    const float* bih  = (const float*)d_in[4];
    const float* bhh  = (const float*)d_in[5];
    const float* Wdec = (const float*)d_in[6];
    const float* bdec = (const float*)d_in[7];
    float* out = (float*)d_out;

    unsigned int* flags = (unsigned int*)d_ws;                // 16 groups x 64B
    unsigned int* hbuf  = (unsigned int*)((char*)d_ws + 8192);// [2][256][512] fp16 pairs

    hipMemsetAsync(d_ws, 0, 8192, stream);
    // no d_out memset needed: every (b,t) gets exactly one plain store
    lstm_forecast_kernel<<<dim3(NWG), dim3(NTHR), 0, stream>>>(
        xseq, Wih, Whh, bih, bhh, Wdec, bdec, out, flags, hbuf);
}